// Round 1
// baseline (476.827 us; speedup 1.0000x reference)
//
#include <hip/hip_runtime.h>
#include <hip/hip_bf16.h>
#include <hip/hip_fp16.h>

// ---- types ----
typedef _Float16 f16x8 __attribute__((ext_vector_type(8)));
typedef float f32x4 __attribute__((ext_vector_type(4)));
typedef unsigned short us8 __attribute__((ext_vector_type(8)));

#define AS1 __attribute__((address_space(1)))
#define AS3 __attribute__((address_space(3)))

// ---------------- fp32 -> fp16 convert (8 elems/thread) ----------------
__global__ __launch_bounds__(256) void cvt_f32_f16(const float* __restrict__ in,
                                                   unsigned short* __restrict__ out,
                                                   int n8) {
  int i = blockIdx.x * 256 + threadIdx.x;
  if (i >= n8) return;
  const float4* p = (const float4*)in + 2 * (size_t)i;
  float4 a = p[0], b = p[1];
  f16x8 h;
  h[0] = (_Float16)a.x; h[1] = (_Float16)a.y; h[2] = (_Float16)a.z; h[3] = (_Float16)a.w;
  h[4] = (_Float16)b.x; h[5] = (_Float16)b.y; h[6] = (_Float16)b.z; h[7] = (_Float16)b.w;
  *(f16x8*)(out + (size_t)i * 8) = h;
}

// ---------------- NT GEMM: C[M,N] = A[M,K] * B[N,K]^T ----------------
// 128x128 tile, BK=64, 256 threads (4 waves, 2x2), mfma_f32_16x16x32_f16.
// OMODE 0: fp16 output; 1: fp32 output.  RBIAS: add bias[row] (per-m).
template <int OMODE, bool RBIAS>
__global__ __launch_bounds__(256) void gemm_nt(const unsigned short* __restrict__ A, int lda,
                                               const unsigned short* __restrict__ B, int ldb,
                                               void* __restrict__ Cout, int ldc,
                                               const float* __restrict__ bias,
                                               int N, int K) {
  __shared__ __attribute__((aligned(16))) unsigned short As[128 * 64];
  __shared__ __attribute__((aligned(16))) unsigned short Bs[128 * 64];
  const int nbn = N >> 7;
  const int bm = blockIdx.x / nbn, bn = blockIdx.x % nbn;
  const int tid = threadIdx.x;
  const int w = tid >> 6, l = tid & 63;
  const int wr = w >> 1, wc = w & 1;
  const int lr = l & 15, lg = l >> 4;

  const unsigned short* Ab = A + (size_t)bm * 128 * lda;
  const unsigned short* Bb = B + (size_t)bn * 128 * ldb;

  f32x4 acc[4][4] = {};

  for (int kt = 0; kt < K; kt += 64) {
    // stage A tile [128][64] linear into LDS via global_load_lds (16B/lane)
#pragma unroll
    for (int i = 0; i < 4; ++i) {
      const int c = i * 256 + w * 64 + l;     // chunk 0..1023
      const int row = c >> 3, col = (c & 7) << 3;
      __builtin_amdgcn_global_load_lds((const AS1 void*)(Ab + (size_t)row * lda + kt + col),
                                       (AS3 void*)(As + (i * 256 + w * 64) * 8), 16, 0, 0);
    }
#pragma unroll
    for (int i = 0; i < 4; ++i) {
      const int c = i * 256 + w * 64 + l;
      const int row = c >> 3, col = (c & 7) << 3;
      __builtin_amdgcn_global_load_lds((const AS1 void*)(Bb + (size_t)row * ldb + kt + col),
                                       (AS3 void*)(Bs + (i * 256 + w * 64) * 8), 16, 0, 0);
    }
    __syncthreads();   // compiler drains vmcnt before s_barrier
#pragma unroll
    for (int kk = 0; kk < 2; ++kk) {
      f16x8 af[4], bf[4];
#pragma unroll
      for (int mi = 0; mi < 4; ++mi)
        af[mi] = *(const f16x8*)(As + (wr * 64 + mi * 16 + lr) * 64 + kk * 32 + lg * 8);
#pragma unroll
      for (int ni = 0; ni < 4; ++ni)
        bf[ni] = *(const f16x8*)(Bs + (wc * 64 + ni * 16 + lr) * 64 + kk * 32 + lg * 8);
#pragma unroll
      for (int mi = 0; mi < 4; ++mi)
#pragma unroll
        for (int ni = 0; ni < 4; ++ni)
          acc[mi][ni] = __builtin_amdgcn_mfma_f32_16x16x32_f16(af[mi], bf[ni], acc[mi][ni], 0, 0, 0);
    }
    __syncthreads();
  }

  // epilogue: C/D frag mapping col=lane&15, row=4*(lane>>4)+reg (m89-verified)
#pragma unroll
  for (int mi = 0; mi < 4; ++mi) {
#pragma unroll
    for (int r = 0; r < 4; ++r) {
      const int row = bm * 128 + wr * 64 + mi * 16 + lg * 4 + r;
      const float badd = RBIAS ? bias[row] : 0.0f;
#pragma unroll
      for (int ni = 0; ni < 4; ++ni) {
        const int col = bn * 128 + wc * 64 + ni * 16 + lr;
        float v = acc[mi][ni][r] + badd;
        if constexpr (OMODE == 0)
          ((unsigned short*)Cout)[(size_t)row * ldc + col] =
              __builtin_bit_cast(unsigned short, (_Float16)v);
        else
          ((float*)Cout)[(size_t)row * ldc + col] = v;
      }
    }
  }
}

// ---------------- row softmax with mask, fp16 in-place, S=4096 ----------------
__global__ __launch_bounds__(256) void softmax_rows(unsigned short* __restrict__ P,
                                                    const int* __restrict__ mask) {
  const int t = threadIdx.x;
  unsigned short* p = P + (size_t)blockIdx.x * 4096;
  us8 u0 = *(const us8*)(p + t * 16);
  us8 u1 = *(const us8*)(p + t * 16 + 8);
  const int4* mp = (const int4*)(mask + t * 16);
  int4 m0 = mp[0], m1 = mp[1], m2 = mp[2], m3 = mp[3];
  int mk[16] = {m0.x, m0.y, m0.z, m0.w, m1.x, m1.y, m1.z, m1.w,
                m2.x, m2.y, m2.z, m2.w, m3.x, m3.y, m3.z, m3.w};
  float v[16];
#pragma unroll
  for (int j = 0; j < 8; ++j) {
    v[j]     = (float)__builtin_bit_cast(_Float16, (unsigned short)u0[j]);
    v[8 + j] = (float)__builtin_bit_cast(_Float16, (unsigned short)u1[j]);
  }
#pragma unroll
  for (int j = 0; j < 16; ++j)
    if (mk[j] == 0) v[j] = -3.0e38f;

  float mx = v[0];
#pragma unroll
  for (int j = 1; j < 16; ++j) mx = fmaxf(mx, v[j]);
  __shared__ float sh[4];
#pragma unroll
  for (int o = 32; o; o >>= 1) mx = fmaxf(mx, __shfl_xor(mx, o));
  if ((t & 63) == 0) sh[t >> 6] = mx;
  __syncthreads();
  mx = fmaxf(fmaxf(sh[0], sh[1]), fmaxf(sh[2], sh[3]));

  float s = 0.f;
#pragma unroll
  for (int j = 0; j < 16; ++j) {
    float e = __expf(v[j] - mx);
    v[j] = e;
    s += e;
  }
#pragma unroll
  for (int o = 32; o; o >>= 1) s += __shfl_xor(s, o);
  __syncthreads();
  if ((t & 63) == 0) sh[t >> 6] = s;
  __syncthreads();
  s = sh[0] + sh[1] + sh[2] + sh[3];
  float inv = 1.0f / s;

  us8 o0, o1;
#pragma unroll
  for (int j = 0; j < 8; ++j) {
    o0[j] = __builtin_bit_cast(unsigned short, (_Float16)(v[j] * inv));
    o1[j] = __builtin_bit_cast(unsigned short, (_Float16)(v[8 + j] * inv));
  }
  *(us8*)(p + t * 16) = o0;
  *(us8*)(p + t * 16 + 8) = o1;
}

// ---------------- LayerNorm + output head, one row (768) per block ----------------
__device__ inline float block_sum(float v, float* sh, int t) {
#pragma unroll
  for (int o = 32; o; o >>= 1) v += __shfl_xor(v, o);
  __syncthreads();
  if ((t & 63) == 0) sh[t >> 6] = v;
  __syncthreads();
  return sh[0] + sh[1] + sh[2] + sh[3];
}

__global__ __launch_bounds__(256) void ln_head(const float* __restrict__ y,
                                               const float* __restrict__ gam,
                                               const float* __restrict__ bet,
                                               const float* __restrict__ wo,
                                               const float* __restrict__ bo,
                                               float* __restrict__ out) {
  const float* yr = y + (size_t)blockIdx.x * 768;
  const int t = threadIdx.x;
  float a0 = yr[t], a1 = yr[t + 256], a2 = yr[t + 512];
  __shared__ float sh[4];
  float s = block_sum(a0 + a1 + a2, sh, t);
  float mu = s * (1.0f / 768.0f);
  float d0 = a0 - mu, d1 = a1 - mu, d2 = a2 - mu;
  float q = block_sum(d0 * d0 + d1 * d1 + d2 * d2, sh, t);
  float rs = rsqrtf(q * (1.0f / 768.0f) + 1e-5f);
  float o = (d0 * rs * gam[t] + bet[t]) * wo[t] +
            (d1 * rs * gam[t + 256] + bet[t + 256]) * wo[t + 256] +
            (d2 * rs * gam[t + 512] + bet[t + 512]) * wo[t + 512];
  o = block_sum(o, sh, t);
  if (t == 0) out[blockIdx.x] = o + bo[0];
}

// ---------------- launch ----------------
extern "C" void kernel_launch(void* const* d_in, const int* in_sizes, int n_in,
                              void* d_out, int out_size, void* d_ws, size_t ws_size,
                              hipStream_t stream) {
  const float* x  = (const float*)d_in[0];
  const int*   am = (const int*)d_in[1];
  const float* Wk = (const float*)d_in[2];
  const float* Wv = (const float*)d_in[3];
  const float* bv = (const float*)d_in[4];
  const float* Q  = (const float*)d_in[5];
  const float* gam = (const float*)d_in[6];
  const float* bet = (const float*)d_in[7];
  const float* wo  = (const float*)d_in[8];
  const float* bo  = (const float*)d_in[9];
  float* out = (float*)d_out;

  const int Bn = 2, S = 4096, D = 768, C = 8192;
  const size_t nTok = (size_t)Bn * S;          // 8192
  const size_t nX = nTok * D;                  // 6291456
  const size_t nW = (size_t)D * D;             // 589824
  const size_t nQ = (size_t)C * D;             // 6291456

  unsigned short* xb  = (unsigned short*)d_ws;
  unsigned short* Wkb = xb + nX;
  unsigned short* Wvb = Wkb + nW;
  unsigned short* Qb  = Wvb + nW;
  unsigned short* Kb  = Qb + nQ;
  unsigned short* Vt  = Kb + nX;               // [D][Bn*S] transposed V
  unsigned short* P   = Vt + nX;               // [C][S] per-b, reused
  float* y = (float*)(P + (size_t)C * S);      // [C][D] per-b, reused

  // 1) convert inputs to fp16
  cvt_f32_f16<<<(int)(nX / 8 / 256), 256, 0, stream>>>(x, xb, (int)(nX / 8));
  cvt_f32_f16<<<(int)(nW / 8 / 256), 256, 0, stream>>>(Wk, Wkb, (int)(nW / 8));
  cvt_f32_f16<<<(int)(nW / 8 / 256), 256, 0, stream>>>(Wv, Wvb, (int)(nW / 8));
  cvt_f32_f16<<<(int)(nQ / 8 / 256), 256, 0, stream>>>(Q, Qb, (int)(nQ / 8));

  // 2) K = x * Wk^T   [8192 x 768], NT
  gemm_nt<0, false><<<(8192 / 128) * (768 / 128), 256, 0, stream>>>(
      xb, D, Wkb, D, Kb, D, nullptr, 768, D);
  // 3) Vt = Wv * x^T + bv  -> [768 x 8192] (V transposed), NT
  gemm_nt<0, true><<<(768 / 128) * (8192 / 128), 256, 0, stream>>>(
      Wvb, D, xb, D, Vt, 8192, bv, 8192, D);

  for (int b = 0; b < 2; ++b) {
    // 4) scores P = Q * K_b^T  [8192 x 4096], NT, fp16 out
    gemm_nt<0, false><<<(8192 / 128) * (4096 / 128), 256, 0, stream>>>(
        Qb, D, Kb + (size_t)b * S * D, D, P, S, nullptr, 4096, D);
    // 5) masked row softmax, in place
    softmax_rows<<<C, 256, 0, stream>>>(P, am + (size_t)b * S);
    // 6) y = P * V_b  ==  P[8192x4096] * (Vt slice)[768x4096]^T, NT, fp32 out
    gemm_nt<1, false><<<(8192 / 128) * (768 / 128), 256, 0, stream>>>(
        P, S, Vt + (size_t)b * S, 8192, y, D, nullptr, 768, S);
    // 7) LayerNorm + head
    ln_head<<<C, 256, 0, stream>>>(y, gam, bet, wo, bo, out + (size_t)b * C);
  }
}

// Round 2
// 387.157 us; speedup vs baseline: 1.2316x; 1.2316x over previous
//
#include <hip/hip_runtime.h>
#include <hip/hip_bf16.h>
#include <hip/hip_fp16.h>

// ---- types ----
typedef _Float16 f16x8 __attribute__((ext_vector_type(8)));
typedef float f32x4 __attribute__((ext_vector_type(4)));
typedef unsigned short us8 __attribute__((ext_vector_type(8)));

#define AS1 __attribute__((address_space(1)))
#define AS3 __attribute__((address_space(3)))

// ---------------- fp32 -> fp16 convert (8 elems/thread) ----------------
__global__ __launch_bounds__(256) void cvt_f32_f16(const float* __restrict__ in,
                                                   unsigned short* __restrict__ out,
                                                   int n8) {
  int i = blockIdx.x * 256 + threadIdx.x;
  if (i >= n8) return;
  const float4* p = (const float4*)in + 2 * (size_t)i;
  float4 a = p[0], b = p[1];
  f16x8 h;
  h[0] = (_Float16)a.x; h[1] = (_Float16)a.y; h[2] = (_Float16)a.z; h[3] = (_Float16)a.w;
  h[4] = (_Float16)b.x; h[5] = (_Float16)b.y; h[6] = (_Float16)b.z; h[7] = (_Float16)b.w;
  *(f16x8*)(out + (size_t)i * 8) = h;
}

// ---------------- 128x128 2-phase NT GEMM (projections only) ----------------
template <int OMODE, bool RBIAS>
__global__ __launch_bounds__(256) void gemm_nt(const unsigned short* __restrict__ A, int lda,
                                               const unsigned short* __restrict__ B, int ldb,
                                               void* __restrict__ Cout, int ldc,
                                               const float* __restrict__ bias,
                                               int N, int K) {
  __shared__ __attribute__((aligned(16))) unsigned short As[128 * 64];
  __shared__ __attribute__((aligned(16))) unsigned short Bs[128 * 64];
  const int nbn = N >> 7;
  const int bm = blockIdx.x / nbn, bn = blockIdx.x % nbn;
  const int tid = threadIdx.x;
  const int w = tid >> 6, l = tid & 63;
  const int wr = w >> 1, wc = w & 1;
  const int lr = l & 15, lg = l >> 4;

  const unsigned short* Ab = A + (size_t)bm * 128 * lda;
  const unsigned short* Bb = B + (size_t)bn * 128 * ldb;

  f32x4 acc[4][4] = {};

  for (int kt = 0; kt < K; kt += 64) {
#pragma unroll
    for (int i = 0; i < 4; ++i) {
      const int c = i * 256 + w * 64 + l;
      const int row = c >> 3, col = (c & 7) << 3;
      __builtin_amdgcn_global_load_lds((const AS1 void*)(Ab + (size_t)row * lda + kt + col),
                                       (AS3 void*)(As + (i * 256 + w * 64) * 8), 16, 0, 0);
    }
#pragma unroll
    for (int i = 0; i < 4; ++i) {
      const int c = i * 256 + w * 64 + l;
      const int row = c >> 3, col = (c & 7) << 3;
      __builtin_amdgcn_global_load_lds((const AS1 void*)(Bb + (size_t)row * ldb + kt + col),
                                       (AS3 void*)(Bs + (i * 256 + w * 64) * 8), 16, 0, 0);
    }
    __syncthreads();
#pragma unroll
    for (int kk = 0; kk < 2; ++kk) {
      f16x8 af[4], bf[4];
#pragma unroll
      for (int mi = 0; mi < 4; ++mi)
        af[mi] = *(const f16x8*)(As + (wr * 64 + mi * 16 + lr) * 64 + kk * 32 + lg * 8);
#pragma unroll
      for (int ni = 0; ni < 4; ++ni)
        bf[ni] = *(const f16x8*)(Bs + (wc * 64 + ni * 16 + lr) * 64 + kk * 32 + lg * 8);
#pragma unroll
      for (int mi = 0; mi < 4; ++mi)
#pragma unroll
        for (int ni = 0; ni < 4; ++ni)
          acc[mi][ni] = __builtin_amdgcn_mfma_f32_16x16x32_f16(af[mi], bf[ni], acc[mi][ni], 0, 0, 0);
    }
    __syncthreads();
  }

#pragma unroll
  for (int mi = 0; mi < 4; ++mi) {
#pragma unroll
    for (int r = 0; r < 4; ++r) {
      const int row = bm * 128 + wr * 64 + mi * 16 + lg * 4 + r;
      const float badd = RBIAS ? bias[row] : 0.0f;
#pragma unroll
      for (int ni = 0; ni < 4; ++ni) {
        const int col = bn * 128 + wc * 64 + ni * 16 + lr;
        float v = acc[mi][ni][r] + badd;
        if constexpr (OMODE == 0)
          ((unsigned short*)Cout)[(size_t)row * ldc + col] =
              __builtin_bit_cast(unsigned short, (_Float16)v);
        else
          ((float*)Cout)[(size_t)row * ldc + col] = v;
      }
    }
  }
}

// ================= 256x256 8-phase NT GEMM (T1+T2+T3+T4+T5) =================
// C[M,N] = A[M,K] * B[N,K]^T.  512 threads = 8 waves (2m x 4n), per-wave 128x64.
// BK=64; LDS 128KB = 2 bufs x { A[2kk][256][64B] | B[2kk][256][64B] }.
// Stage unit = one 16KB kk-half (2 global_load_lds per wave). Units per K-tile:
// r0=A-k0(@0) r1=B-k0(@32K) r2=A-k1(@16K) r3=B-k1(@48K).
// Phase order per tile: (k0,mh0)(k0,mh1)(k1,mh0)(k1,mh1); kk-half fully consumed
// after its 2 phases, so unit u (lookahead 6) always lands in a region whose old
// data was consumed at least one barrier earlier.  Steady-state vmcnt(8)
// (= 4 units in flight), epilogue drains 8 -> 4 -> 0. Never 0 in main loop.
// LDS swizzle: byte offset ^= (row&3)<<4 on reads, inverse-applied to the
// global source column so global_load_lds' linear write lands pre-swizzled.
#define MFMA16(a, b, c) __builtin_amdgcn_mfma_f32_16x16x32_f16(a, b, c, 0, 0, 0)
#define VM8 asm volatile("s_waitcnt vmcnt(8)" ::: "memory")
#define VM4 asm volatile("s_waitcnt vmcnt(4)" ::: "memory")
#define VM0 asm volatile("s_waitcnt vmcnt(0)" ::: "memory")
#define VMNONE ((void)0)
#define BARRIER asm volatile("s_barrier" ::: "memory")

#define PH(kk, mh, VMW)                                                        \
  {                                                                            \
    f16x8 a0 = ldA8(4 * (mh) + 0, (kk));                                       \
    f16x8 a1 = ldA8(4 * (mh) + 1, (kk));                                       \
    f16x8 a2 = ldA8(4 * (mh) + 2, (kk));                                       \
    f16x8 a3 = ldA8(4 * (mh) + 3, (kk));                                       \
    f16x8 b0 = ldB8(0, (kk));                                                  \
    f16x8 b1 = ldB8(1, (kk));                                                  \
    f16x8 b2 = ldB8(2, (kk));                                                  \
    f16x8 b3 = ldB8(3, (kk));                                                  \
    if (u < NT4) stage(u);                                                     \
    ++u;                                                                       \
    BARRIER;                                                                   \
    __builtin_amdgcn_s_setprio(1);                                             \
    acc[4 * (mh) + 0][0] = MFMA16(a0, b0, acc[4 * (mh) + 0][0]);               \
    acc[4 * (mh) + 0][1] = MFMA16(a0, b1, acc[4 * (mh) + 0][1]);               \
    acc[4 * (mh) + 0][2] = MFMA16(a0, b2, acc[4 * (mh) + 0][2]);               \
    acc[4 * (mh) + 0][3] = MFMA16(a0, b3, acc[4 * (mh) + 0][3]);               \
    acc[4 * (mh) + 1][0] = MFMA16(a1, b0, acc[4 * (mh) + 1][0]);               \
    acc[4 * (mh) + 1][1] = MFMA16(a1, b1, acc[4 * (mh) + 1][1]);               \
    acc[4 * (mh) + 1][2] = MFMA16(a1, b2, acc[4 * (mh) + 1][2]);               \
    acc[4 * (mh) + 1][3] = MFMA16(a1, b3, acc[4 * (mh) + 1][3]);               \
    acc[4 * (mh) + 2][0] = MFMA16(a2, b0, acc[4 * (mh) + 2][0]);               \
    acc[4 * (mh) + 2][1] = MFMA16(a2, b1, acc[4 * (mh) + 2][1]);               \
    acc[4 * (mh) + 2][2] = MFMA16(a2, b2, acc[4 * (mh) + 2][2]);               \
    acc[4 * (mh) + 2][3] = MFMA16(a2, b3, acc[4 * (mh) + 2][3]);               \
    acc[4 * (mh) + 3][0] = MFMA16(a3, b0, acc[4 * (mh) + 3][0]);               \
    acc[4 * (mh) + 3][1] = MFMA16(a3, b1, acc[4 * (mh) + 3][1]);               \
    acc[4 * (mh) + 3][2] = MFMA16(a3, b2, acc[4 * (mh) + 3][2]);               \
    acc[4 * (mh) + 3][3] = MFMA16(a3, b3, acc[4 * (mh) + 3][3]);               \
    __builtin_amdgcn_s_setprio(0);                                             \
    VMW;                                                                       \
    BARRIER;                                                                   \
  }

template <int OMODE>
__global__ __launch_bounds__(512, 2) void gemm256(
    const unsigned short* __restrict__ A, int lda, size_t sAz,
    const unsigned short* __restrict__ B, int ldb, size_t sBz,
    void* __restrict__ Cout, int ldc, size_t sCz,
    int nbn, int NT, int cpx) {
  __shared__ __attribute__((aligned(16))) unsigned char lds[131072];
  const int tid = threadIdx.x;
  const int wv = tid >> 6, l = tid & 63;
  const int wm = wv >> 2, wn = wv & 3;
  const int lr = l & 15, lg = l >> 4;
  const int z = blockIdx.y;

  const int bid = blockIdx.x;
  const int swz = (bid & 7) * cpx + (bid >> 3);  // nwg % 8 == 0 always here
  const int bm = swz / nbn, bn = swz % nbn;

  const unsigned short* Ab = A + z * sAz + (size_t)bm * 256 * lda;
  const unsigned short* Bb = B + z * sBz + (size_t)bn * 256 * ldb;

  const int NT4 = NT * 4;
  int bufOff = 0;

  // issue one 16KB stage unit (2 global_load_lds per wave, lane covers 16B)
  auto stage = [&](int uu) {
    const int tau = uu >> 2, r = uu & 3;
    const int regionOff = ((tau & 1) << 16) | ((r & 1) << 15) | ((r >> 1) << 14);
    const unsigned short* base = (r & 1) ? Bb : Ab;
    const int ld = (r & 1) ? ldb : lda;
    const int kcol0 = tau * 64 + ((r >> 1) << 5);
#pragma unroll
    for (int j = 0; j < 2; ++j) {
      const int row = wv * 32 + j * 16 + (l >> 2);
      const int col = kcol0 + ((((l & 3) ^ (row & 3))) << 3);  // pre-swizzled src
      __builtin_amdgcn_global_load_lds(
          (const AS1 void*)(base + (size_t)row * ld + col),
          (AS3 void*)(lds + regionOff + wv * 2048 + j * 1024), 16, 0, 0);
    }
  };
  // swizzled fragment reads: phys = (row*64 + lg*16) ^ ((row&3)<<4)
  auto ldA8 = [&](int mf, int kk) {
    const int row = wm * 128 + mf * 16 + lr;
    int off = (row << 6) + (lg << 4);
    off ^= (lr & 3) << 4;
    return *(const f16x8*)(lds + bufOff + (kk << 14) + off);
  };
  auto ldB8 = [&](int nf, int kk) {
    const int row = wn * 64 + nf * 16 + lr;
    int off = (row << 6) + (lg << 4);
    off ^= (lr & 3) << 4;
    return *(const f16x8*)(lds + bufOff + 32768 + (kk << 14) + off);
  };

  f32x4 acc[8][4] = {};

  // prologue: units 0..5 (tile0 all + tile1 k0), then wait tile0-k0 landed
  for (int i = 0; i < 6; ++i) stage(i);
  int u = 6;
  VM8;
  BARRIER;

  for (int t = 0; t + 2 < NT; ++t) {
    bufOff = (t & 1) << 16;
    PH(0, 0, VMNONE);
    PH(0, 1, VM8);
    PH(1, 0, VMNONE);
    PH(1, 1, VM8);
  }
  bufOff = ((NT - 2) & 1) << 16;
  PH(0, 0, VMNONE);
  PH(0, 1, VM8);
  PH(1, 0, VMNONE);
  PH(1, 1, VM4);
  bufOff = ((NT - 1) & 1) << 16;
  PH(0, 0, VMNONE);
  PH(0, 1, VM0);
  PH(1, 0, VMNONE);
  PH(1, 1, VMNONE);

  // epilogue: C/D frag col=lr, row=4*lg+reg
  const size_t crow0 = (size_t)bm * 256 + wm * 128;
  const int ccol0 = bn * 256 + wn * 64;
#pragma unroll
  for (int mf = 0; mf < 8; ++mf) {
#pragma unroll
    for (int rr = 0; rr < 4; ++rr) {
      const size_t row = crow0 + mf * 16 + lg * 4 + rr;
      const size_t rb = (size_t)z * sCz + row * (size_t)ldc;
#pragma unroll
      for (int nf = 0; nf < 4; ++nf) {
        const int col = ccol0 + nf * 16 + lr;
        const float v = acc[mf][nf][rr];
        if constexpr (OMODE == 0)
          ((unsigned short*)Cout)[rb + col] =
              __builtin_bit_cast(unsigned short, (_Float16)v);
        else
          ((float*)Cout)[rb + col] = v;
      }
    }
  }
}

// ---------------- row softmax with mask, fp16 in-place, S=4096 ----------------
__global__ __launch_bounds__(256) void softmax_rows(unsigned short* __restrict__ P,
                                                    const int* __restrict__ mask,
                                                    size_t pZ, size_t mZ) {
  const int t = threadIdx.x;
  unsigned short* p = P + (size_t)blockIdx.y * pZ + (size_t)blockIdx.x * 4096;
  const int* mrow = mask + (size_t)blockIdx.y * mZ;
  us8 u0 = *(const us8*)(p + t * 16);
  us8 u1 = *(const us8*)(p + t * 16 + 8);
  const int4* mp = (const int4*)(mrow + t * 16);
  int4 m0 = mp[0], m1 = mp[1], m2 = mp[2], m3 = mp[3];
  int mk[16] = {m0.x, m0.y, m0.z, m0.w, m1.x, m1.y, m1.z, m1.w,
                m2.x, m2.y, m2.z, m2.w, m3.x, m3.y, m3.z, m3.w};
  float v[16];
#pragma unroll
  for (int j = 0; j < 8; ++j) {
    v[j]     = (float)__builtin_bit_cast(_Float16, (unsigned short)u0[j]);
    v[8 + j] = (float)__builtin_bit_cast(_Float16, (unsigned short)u1[j]);
  }
#pragma unroll
  for (int j = 0; j < 16; ++j)
    if (mk[j] == 0) v[j] = -3.0e38f;

  float mx = v[0];
#pragma unroll
  for (int j = 1; j < 16; ++j) mx = fmaxf(mx, v[j]);
  __shared__ float sh[4];
#pragma unroll
  for (int o = 32; o; o >>= 1) mx = fmaxf(mx, __shfl_xor(mx, o));
  if ((t & 63) == 0) sh[t >> 6] = mx;
  __syncthreads();
  mx = fmaxf(fmaxf(sh[0], sh[1]), fmaxf(sh[2], sh[3]));

  float s = 0.f;
#pragma unroll
  for (int j = 0; j < 16; ++j) {
    float e = __expf(v[j] - mx);
    v[j] = e;
    s += e;
  }
#pragma unroll
  for (int o = 32; o; o >>= 1) s += __shfl_xor(s, o);
  __syncthreads();
  if ((t & 63) == 0) sh[t >> 6] = s;
  __syncthreads();
  s = sh[0] + sh[1] + sh[2] + sh[3];
  float inv = 1.0f / s;

  us8 o0, o1;
#pragma unroll
  for (int j = 0; j < 8; ++j) {
    o0[j] = __builtin_bit_cast(unsigned short, (_Float16)(v[j] * inv));
    o1[j] = __builtin_bit_cast(unsigned short, (_Float16)(v[8 + j] * inv));
  }
  *(us8*)(p + t * 16) = o0;
  *(us8*)(p + t * 16 + 8) = o1;
}

// ---------------- LayerNorm + output head, one row (768) per block ----------------
__device__ inline float block_sum(float v, float* sh, int t) {
#pragma unroll
  for (int o = 32; o; o >>= 1) v += __shfl_xor(v, o);
  __syncthreads();
  if ((t & 63) == 0) sh[t >> 6] = v;
  __syncthreads();
  return sh[0] + sh[1] + sh[2] + sh[3];
}

__global__ __launch_bounds__(256) void ln_head(const float* __restrict__ y,
                                               const float* __restrict__ gam,
                                               const float* __restrict__ bet,
                                               const float* __restrict__ wo,
                                               const float* __restrict__ bo,
                                               float* __restrict__ out) {
  const size_t rowi = (size_t)blockIdx.y * 8192 + blockIdx.x;
  const float* yr = y + rowi * 768;
  const int t = threadIdx.x;
  float a0 = yr[t], a1 = yr[t + 256], a2 = yr[t + 512];
  __shared__ float sh[4];
  float s = block_sum(a0 + a1 + a2, sh, t);
  float mu = s * (1.0f / 768.0f);
  float d0 = a0 - mu, d1 = a1 - mu, d2 = a2 - mu;
  float q = block_sum(d0 * d0 + d1 * d1 + d2 * d2, sh, t);
  float rs = rsqrtf(q * (1.0f / 768.0f) + 1e-5f);
  float o = (d0 * rs * gam[t] + bet[t]) * wo[t] +
            (d1 * rs * gam[t + 256] + bet[t + 256]) * wo[t + 256] +
            (d2 * rs * gam[t + 512] + bet[t + 512]) * wo[t + 512];
  o = block_sum(o, sh, t);
  if (t == 0) out[rowi] = o + bo[0];
}

// ---------------- launch ----------------
extern "C" void kernel_launch(void* const* d_in, const int* in_sizes, int n_in,
                              void* d_out, int out_size, void* d_ws, size_t ws_size,
                              hipStream_t stream) {
  const float* x  = (const float*)d_in[0];
  const int*   am = (const int*)d_in[1];
  const float* Wk = (const float*)d_in[2];
  const float* Wv = (const float*)d_in[3];
  const float* bv = (const float*)d_in[4];
  const float* Q  = (const float*)d_in[5];
  const float* gam = (const float*)d_in[6];
  const float* bet = (const float*)d_in[7];
  const float* wo  = (const float*)d_in[8];
  const float* bo  = (const float*)d_in[9];
  float* out = (float*)d_out;

  const int S = 4096, D = 768, C = 8192;
  const size_t nX = (size_t)2 * S * D;   // 6291456
  const size_t nW = (size_t)D * D;       // 589824
  const size_t nQ = (size_t)C * D;       // 6291456
  const size_t nP = (size_t)C * S;       // 33554432
  const size_t nY = (size_t)C * D;       // 6291456

  unsigned short* xb  = (unsigned short*)d_ws;
  unsigned short* Wkb = xb + nX;
  unsigned short* Wvb = Wkb + nW;
  unsigned short* Qb  = Wvb + nW;
  unsigned short* Kb  = Qb + nQ;
  unsigned short* Vt  = Kb + nX;         // [D][2*S]
  unsigned short* P   = Vt + nX;

  const size_t bigNeed = ((nX * 4 + nW * 2 + 2 * nP) * 2 + 2 * nY * 4);
  const bool big = ws_size >= bigNeed;

  // 1) convert inputs to fp16
  cvt_f32_f16<<<(int)(nX / 8 / 256), 256, 0, stream>>>(x, xb, (int)(nX / 8));
  cvt_f32_f16<<<(int)(nW / 8 / 256), 256, 0, stream>>>(Wk, Wkb, (int)(nW / 8));
  cvt_f32_f16<<<(int)(nW / 8 / 256), 256, 0, stream>>>(Wv, Wvb, (int)(nW / 8));
  cvt_f32_f16<<<(int)(nQ / 8 / 256), 256, 0, stream>>>(Q, Qb, (int)(nQ / 8));

  // 2) projections (small, keep 128^2 kernel)
  gemm_nt<0, false><<<(8192 / 128) * (768 / 128), 256, 0, stream>>>(
      xb, D, Wkb, D, Kb, D, nullptr, 768, D);
  gemm_nt<0, true><<<(768 / 128) * (8192 / 128), 256, 0, stream>>>(
      Wvb, D, xb, D, Vt, 2 * S, bv, 2 * S, D);

  if (big) {
    float* y = (float*)(P + 2 * nP);
    // 3) scores both batches: [8192 x 4096] x2, K=768 -> NT=12
    gemm256<0><<<dim3(512, 2), 512, 0, stream>>>(
        Qb, D, 0, Kb, D, (size_t)S * D, P, S, nP, 16, 12, 64);
    // 4) masked softmax both batches
    softmax_rows<<<dim3(C, 2), 256, 0, stream>>>(P, am, nP, (size_t)S);
    // 5) PV both batches: y = P * Vt_b^T  [8192 x 768], K=4096 -> NT=64
    gemm256<1><<<dim3(96, 2), 512, 0, stream>>>(
        P, S, nP, Vt, 2 * S, (size_t)S, y, D, nY, 3, 64, 12);
    // 6) LN + head both batches
    ln_head<<<dim3(C, 2), 256, 0, stream>>>(y, gam, bet, wo, bo, out);
  } else {
    float* y = (float*)(P + nP);
    for (int b = 0; b < 2; ++b) {
      gemm256<0><<<dim3(512, 1), 512, 0, stream>>>(
          Qb, D, 0, Kb + (size_t)b * S * D, D, 0, P, S, 0, 16, 12, 64);
      softmax_rows<<<dim3(C, 1), 256, 0, stream>>>(P, am + (size_t)b * S, 0, 0);
      gemm256<1><<<dim3(96, 1), 512, 0, stream>>>(
          P, S, 0, Vt + (size_t)b * S, 2 * S, 0, y, D, 0, 3, 64, 12);
      ln_head<<<dim3(C, 1), 256, 0, stream>>>(y, gam, bet, wo, bo, out + (size_t)b * C);
    }
  }
}

// Round 3
// 314.568 us; speedup vs baseline: 1.5158x; 1.2308x over previous
//
#include <hip/hip_runtime.h>
#include <hip/hip_bf16.h>
#include <hip/hip_fp16.h>

// ---- types ----
typedef _Float16 f16x8 __attribute__((ext_vector_type(8)));
typedef float f32x4 __attribute__((ext_vector_type(4)));
typedef unsigned short us8 __attribute__((ext_vector_type(8)));

#define AS1 __attribute__((address_space(1)))
#define AS3 __attribute__((address_space(3)))

// ---------------- fp32 -> fp16 convert (8 elems/thread) ----------------
__global__ __launch_bounds__(256) void cvt_f32_f16(const float* __restrict__ in,
                                                   unsigned short* __restrict__ out,
                                                   int n8) {
  int i = blockIdx.x * 256 + threadIdx.x;
  if (i >= n8) return;
  const float4* p = (const float4*)in + 2 * (size_t)i;
  float4 a = p[0], b = p[1];
  f16x8 h;
  h[0] = (_Float16)a.x; h[1] = (_Float16)a.y; h[2] = (_Float16)a.z; h[3] = (_Float16)a.w;
  h[4] = (_Float16)b.x; h[5] = (_Float16)b.y; h[6] = (_Float16)b.z; h[7] = (_Float16)b.w;
  *(f16x8*)(out + (size_t)i * 8) = h;
}

// ---------------- 128x128 2-phase NT GEMM (projections only) ----------------
// LDS tile rows are 128 B -> XOR-swizzle slot bits with (row&7) (G4 recipe),
// pre-swizzled on the global source, swizzled on the ds_read.
template <int OMODE, bool RBIAS>
__global__ __launch_bounds__(256) void gemm_nt(const unsigned short* __restrict__ A, int lda,
                                               const unsigned short* __restrict__ B, int ldb,
                                               void* __restrict__ Cout, int ldc,
                                               const float* __restrict__ bias,
                                               int N, int K) {
  __shared__ __attribute__((aligned(16))) unsigned short As[128 * 64];
  __shared__ __attribute__((aligned(16))) unsigned short Bs[128 * 64];
  const int nbn = N >> 7;
  const int bm = blockIdx.x / nbn, bn = blockIdx.x % nbn;
  const int tid = threadIdx.x;
  const int w = tid >> 6, l = tid & 63;
  const int wr = w >> 1, wc = w & 1;
  const int lr = l & 15, lg = l >> 4;

  const unsigned short* Ab = A + (size_t)bm * 128 * lda;
  const unsigned short* Bb = B + (size_t)bn * 128 * ldb;

  f32x4 acc[4][4] = {};

  auto ldfrag = [&](const unsigned short* base, int row, int kk) {
    int off = row * 128 + kk * 64 + lg * 16;   // bytes
    off ^= (row & 7) << 4;                      // read-side swizzle
    return *(const f16x8*)((const unsigned char*)base + off);
  };

  for (int kt = 0; kt < K; kt += 64) {
#pragma unroll
    for (int i = 0; i < 4; ++i) {
      const int c = i * 256 + w * 64 + l;
      const int row = c >> 3, col = (((c & 7) ^ (row & 7)) << 3);  // pre-swizzled src
      __builtin_amdgcn_global_load_lds((const AS1 void*)(Ab + (size_t)row * lda + kt + col),
                                       (AS3 void*)(As + (i * 256 + w * 64) * 8), 16, 0, 0);
    }
#pragma unroll
    for (int i = 0; i < 4; ++i) {
      const int c = i * 256 + w * 64 + l;
      const int row = c >> 3, col = (((c & 7) ^ (row & 7)) << 3);
      __builtin_amdgcn_global_load_lds((const AS1 void*)(Bb + (size_t)row * ldb + kt + col),
                                       (AS3 void*)(Bs + (i * 256 + w * 64) * 8), 16, 0, 0);
    }
    __syncthreads();
#pragma unroll
    for (int kk = 0; kk < 2; ++kk) {
      f16x8 af[4], bf[4];
#pragma unroll
      for (int mi = 0; mi < 4; ++mi) af[mi] = ldfrag(As, wr * 64 + mi * 16 + lr, kk);
#pragma unroll
      for (int ni = 0; ni < 4; ++ni) bf[ni] = ldfrag(Bs, wc * 64 + ni * 16 + lr, kk);
#pragma unroll
      for (int mi = 0; mi < 4; ++mi)
#pragma unroll
        for (int ni = 0; ni < 4; ++ni)
          acc[mi][ni] = __builtin_amdgcn_mfma_f32_16x16x32_f16(af[mi], bf[ni], acc[mi][ni], 0, 0, 0);
    }
    __syncthreads();
  }

#pragma unroll
  for (int mi = 0; mi < 4; ++mi) {
#pragma unroll
    for (int r = 0; r < 4; ++r) {
      const int row = bm * 128 + wr * 64 + mi * 16 + lg * 4 + r;
      const float badd = RBIAS ? bias[row] : 0.0f;
#pragma unroll
      for (int ni = 0; ni < 4; ++ni) {
        const int col = bn * 128 + wc * 64 + ni * 16 + lr;
        float v = acc[mi][ni][r] + badd;
        if constexpr (OMODE == 0)
          ((unsigned short*)Cout)[(size_t)row * ldc + col] =
              __builtin_bit_cast(unsigned short, (_Float16)v);
        else
          ((float*)Cout)[(size_t)row * ldc + col] = v;
      }
    }
  }
}

// ================= 256x256 8-phase NT GEMM (T1+T2+T3+T4+T5) =================
// C[M,N] = A[M,K] * B[N,K]^T.  512 threads = 8 waves (2m x 4n), per-wave 128x64.
// BK=64; LDS 128KB = 2 bufs x { A[2kk][256][64B] | B[2kk][256][64B] }.
// Stage unit = one 16KB kk-half; units r0=A-k0 r1=B-k0 r2=A-k1 r3=B-k1.
// Steady-state vmcnt(8) (4 units in flight), epilogue drains 8->4->0.
// LDS rows are 64 B: slot bits = byte[4:6], bit6 = row&1 -> XOR (row>>1)&3
// into bits 4-5 (read side) + same permutation on the global source column.
// B-fragments are read once per kk and held in VGPRs across the mh pair.
// EPI: 0 = fp16 store, 1 = fp32 store, 2 = fp16 store of (mask ? exp(s) : 0)
// (softmax normalization is absorbed by the downstream LayerNorm).
#define MFMA16(a, b, c) __builtin_amdgcn_mfma_f32_16x16x32_f16(a, b, c, 0, 0, 0)
#define VM8 asm volatile("s_waitcnt vmcnt(8)" ::: "memory")
#define VM4 asm volatile("s_waitcnt vmcnt(4)" ::: "memory")
#define VM0 asm volatile("s_waitcnt vmcnt(0)" ::: "memory")
#define VMNONE ((void)0)
#define BARRIER asm volatile("s_barrier" ::: "memory")

#define PH(kk, mh, DOB, VMW)                                                   \
  {                                                                            \
    f16x8 a0 = ldA8(4 * (mh) + 0, (kk));                                       \
    f16x8 a1 = ldA8(4 * (mh) + 1, (kk));                                       \
    f16x8 a2 = ldA8(4 * (mh) + 2, (kk));                                       \
    f16x8 a3 = ldA8(4 * (mh) + 3, (kk));                                       \
    if (DOB) {                                                                 \
      vb0 = ldB8(0, (kk)); vb1 = ldB8(1, (kk));                                \
      vb2 = ldB8(2, (kk)); vb3 = ldB8(3, (kk));                                \
    }                                                                          \
    if (u < NT4) stage(u);                                                     \
    ++u;                                                                       \
    BARRIER;                                                                   \
    __builtin_amdgcn_s_setprio(1);                                             \
    acc[4 * (mh) + 0][0] = MFMA16(a0, vb0, acc[4 * (mh) + 0][0]);              \
    acc[4 * (mh) + 0][1] = MFMA16(a0, vb1, acc[4 * (mh) + 0][1]);              \
    acc[4 * (mh) + 0][2] = MFMA16(a0, vb2, acc[4 * (mh) + 0][2]);              \
    acc[4 * (mh) + 0][3] = MFMA16(a0, vb3, acc[4 * (mh) + 0][3]);              \
    acc[4 * (mh) + 1][0] = MFMA16(a1, vb0, acc[4 * (mh) + 1][0]);              \
    acc[4 * (mh) + 1][1] = MFMA16(a1, vb1, acc[4 * (mh) + 1][1]);              \
    acc[4 * (mh) + 1][2] = MFMA16(a1, vb2, acc[4 * (mh) + 1][2]);              \
    acc[4 * (mh) + 1][3] = MFMA16(a1, vb3, acc[4 * (mh) + 1][3]);              \
    acc[4 * (mh) + 2][0] = MFMA16(a2, vb0, acc[4 * (mh) + 2][0]);              \
    acc[4 * (mh) + 2][1] = MFMA16(a2, vb1, acc[4 * (mh) + 2][1]);              \
    acc[4 * (mh) + 2][2] = MFMA16(a2, vb2, acc[4 * (mh) + 2][2]);              \
    acc[4 * (mh) + 2][3] = MFMA16(a2, vb3, acc[4 * (mh) + 2][3]);              \
    acc[4 * (mh) + 3][0] = MFMA16(a3, vb0, acc[4 * (mh) + 3][0]);              \
    acc[4 * (mh) + 3][1] = MFMA16(a3, vb1, acc[4 * (mh) + 3][1]);              \
    acc[4 * (mh) + 3][2] = MFMA16(a3, vb2, acc[4 * (mh) + 3][2]);              \
    acc[4 * (mh) + 3][3] = MFMA16(a3, vb3, acc[4 * (mh) + 3][3]);              \
    __builtin_amdgcn_s_setprio(0);                                             \
    VMW;                                                                       \
    BARRIER;                                                                   \
  }

template <int EPI>
__global__ __launch_bounds__(512, 2) void gemm256(
    const unsigned short* __restrict__ A, int lda, size_t sAz,
    const unsigned short* __restrict__ B, int ldb, size_t sBz,
    void* __restrict__ Cout, int ldc, size_t sCz,
    const int* __restrict__ mask, int mS,
    int nbn, int NT, int cpx) {
  __shared__ __attribute__((aligned(16))) unsigned char lds[131072];
  const int tid = threadIdx.x;
  const int wv = tid >> 6, l = tid & 63;
  const int wm = wv >> 2, wn = wv & 3;
  const int lr = l & 15, lg = l >> 4;
  const int z = blockIdx.y;

  const int bid = blockIdx.x;
  const int swz = (bid & 7) * cpx + (bid >> 3);  // nwg % 8 == 0 always here
  const int bm = swz / nbn, bn = swz % nbn;

  const unsigned short* Ab = A + z * sAz + (size_t)bm * 256 * lda;
  const unsigned short* Bb = B + z * sBz + (size_t)bn * 256 * ldb;

  const int NT4 = NT * 4;
  int bufOff = 0;

  auto stage = [&](int uu) {
    const int tau = uu >> 2, r = uu & 3;
    const int regionOff = ((tau & 1) << 16) | ((r & 1) << 15) | ((r >> 1) << 14);
    const unsigned short* base = (r & 1) ? Bb : Ab;
    const int ld = (r & 1) ? ldb : lda;
    const int kcol0 = tau * 64 + ((r >> 1) << 5);
#pragma unroll
    for (int j = 0; j < 2; ++j) {
      const int row = wv * 32 + j * 16 + (l >> 2);
      const int col = kcol0 + ((((l & 3) ^ ((row >> 1) & 3))) << 3);  // pre-swizzled src
      __builtin_amdgcn_global_load_lds(
          (const AS1 void*)(base + (size_t)row * ld + col),
          (AS3 void*)(lds + regionOff + wv * 2048 + j * 1024), 16, 0, 0);
    }
  };
  auto ldA8 = [&](int mf, int kk) {
    const int row = wm * 128 + mf * 16 + lr;
    int off = (row << 6) + (lg << 4);
    off ^= ((row >> 1) & 3) << 4;
    return *(const f16x8*)(lds + bufOff + (kk << 14) + off);
  };
  auto ldB8 = [&](int nf, int kk) {
    const int row = wn * 64 + nf * 16 + lr;
    int off = (row << 6) + (lg << 4);
    off ^= ((row >> 1) & 3) << 4;
    return *(const f16x8*)(lds + bufOff + 32768 + (kk << 14) + off);
  };

  f32x4 acc[8][4] = {};
  f16x8 vb0, vb1, vb2, vb3;

  // prologue: units 0..5 (tile0 all + tile1 k0), then wait tile0-k0 landed
  for (int i = 0; i < 6; ++i) stage(i);
  int u = 6;
  VM8;
  BARRIER;

  for (int t = 0; t + 2 < NT; ++t) {
    bufOff = (t & 1) << 16;
    PH(0, 0, 1, VMNONE);
    PH(0, 1, 0, VM8);
    PH(1, 0, 1, VMNONE);
    PH(1, 1, 0, VM8);
  }
  bufOff = ((NT - 2) & 1) << 16;
  PH(0, 0, 1, VMNONE);
  PH(0, 1, 0, VM8);
  PH(1, 0, 1, VMNONE);
  PH(1, 1, 0, VM4);
  bufOff = ((NT - 1) & 1) << 16;
  PH(0, 0, 1, VMNONE);
  PH(0, 1, 0, VM0);
  PH(1, 0, 1, VMNONE);
  PH(1, 1, 0, VMNONE);

  // epilogue: C/D frag col=lr, row=4*lg+reg
  const size_t crow0 = (size_t)bm * 256 + wm * 128;
  const int ccol0 = bn * 256 + wn * 64;
  int mk[4] = {1, 1, 1, 1};
  if constexpr (EPI == 2) {
#pragma unroll
    for (int nf = 0; nf < 4; ++nf)
      mk[nf] = mask[(size_t)z * mS + ccol0 + nf * 16 + lr];
  }
#pragma unroll
  for (int mf = 0; mf < 8; ++mf) {
#pragma unroll
    for (int rr = 0; rr < 4; ++rr) {
      const size_t row = crow0 + mf * 16 + lg * 4 + rr;
      const size_t rb = (size_t)z * sCz + row * (size_t)ldc;
#pragma unroll
      for (int nf = 0; nf < 4; ++nf) {
        const int col = ccol0 + nf * 16 + lr;
        float v = acc[mf][nf][rr];
        if constexpr (EPI == 2) {
          v = mk[nf] ? __expf(v) : 0.0f;
          ((unsigned short*)Cout)[rb + col] =
              __builtin_bit_cast(unsigned short, (_Float16)v);
        } else if constexpr (EPI == 0) {
          ((unsigned short*)Cout)[rb + col] =
              __builtin_bit_cast(unsigned short, (_Float16)v);
        } else {
          ((float*)Cout)[rb + col] = v;
        }
      }
    }
  }
}

// ---------------- LayerNorm + output head, one row (768) per block --------
// y arrives UNNORMALIZED (softmax denominator folded out): LN is
// scale-invariant up to eps/(s^2*var) ~ 4e-9 here.
__device__ inline float block_sum(float v, float* sh, int t) {
#pragma unroll
  for (int o = 32; o; o >>= 1) v += __shfl_xor(v, o);
  __syncthreads();
  if ((t & 63) == 0) sh[t >> 6] = v;
  __syncthreads();
  return sh[0] + sh[1] + sh[2] + sh[3];
}

__global__ __launch_bounds__(256) void ln_head(const float* __restrict__ y,
                                               const float* __restrict__ gam,
                                               const float* __restrict__ bet,
                                               const float* __restrict__ wo,
                                               const float* __restrict__ bo,
                                               float* __restrict__ out) {
  const size_t rowi = (size_t)blockIdx.y * 8192 + blockIdx.x;
  const float* yr = y + rowi * 768;
  const int t = threadIdx.x;
  float a0 = yr[t], a1 = yr[t + 256], a2 = yr[t + 512];
  __shared__ float sh[4];
  float s = block_sum(a0 + a1 + a2, sh, t);
  float mu = s * (1.0f / 768.0f);
  float d0 = a0 - mu, d1 = a1 - mu, d2 = a2 - mu;
  float q = block_sum(d0 * d0 + d1 * d1 + d2 * d2, sh, t);
  float rs = rsqrtf(q * (1.0f / 768.0f) + 1e-5f);
  float o = (d0 * rs * gam[t] + bet[t]) * wo[t] +
            (d1 * rs * gam[t + 256] + bet[t + 256]) * wo[t + 256] +
            (d2 * rs * gam[t + 512] + bet[t + 512]) * wo[t + 512];
  o = block_sum(o, sh, t);
  if (t == 0) out[rowi] = o + bo[0];
}

// ---------------- launch ----------------
extern "C" void kernel_launch(void* const* d_in, const int* in_sizes, int n_in,
                              void* d_out, int out_size, void* d_ws, size_t ws_size,
                              hipStream_t stream) {
  const float* x  = (const float*)d_in[0];
  const int*   am = (const int*)d_in[1];
  const float* Wk = (const float*)d_in[2];
  const float* Wv = (const float*)d_in[3];
  const float* bv = (const float*)d_in[4];
  const float* Q  = (const float*)d_in[5];
  const float* gam = (const float*)d_in[6];
  const float* bet = (const float*)d_in[7];
  const float* wo  = (const float*)d_in[8];
  const float* bo  = (const float*)d_in[9];
  float* out = (float*)d_out;

  const int S = 4096, D = 768, C = 8192;
  const size_t nX = (size_t)2 * S * D;   // 6291456
  const size_t nW = (size_t)D * D;       // 589824
  const size_t nQ = (size_t)C * D;       // 6291456
  const size_t nP = (size_t)C * S;       // 33554432
  const size_t nY = (size_t)C * D;       // 6291456

  unsigned short* xb  = (unsigned short*)d_ws;
  unsigned short* Wkb = xb + nX;
  unsigned short* Wvb = Wkb + nW;
  unsigned short* Qb  = Wvb + nW;
  unsigned short* Kb  = Qb + nQ;
  unsigned short* Vt  = Kb + nX;         // [D][2*S]
  unsigned short* P   = Vt + nX;

  const size_t bigNeed = ((nX * 4 + nW * 2 + 2 * nP) * 2 + 2 * nY * 4);
  const bool big = ws_size >= bigNeed;

  // 1) convert inputs to fp16
  cvt_f32_f16<<<(int)(nX / 8 / 256), 256, 0, stream>>>(x, xb, (int)(nX / 8));
  cvt_f32_f16<<<(int)(nW / 8 / 256), 256, 0, stream>>>(Wk, Wkb, (int)(nW / 8));
  cvt_f32_f16<<<(int)(nW / 8 / 256), 256, 0, stream>>>(Wv, Wvb, (int)(nW / 8));
  cvt_f32_f16<<<(int)(nQ / 8 / 256), 256, 0, stream>>>(Q, Qb, (int)(nQ / 8));

  // 2) projections (small, keep 128^2 kernel)
  gemm_nt<0, false><<<(8192 / 128) * (768 / 128), 256, 0, stream>>>(
      xb, D, Wkb, D, Kb, D, nullptr, 768, D);
  gemm_nt<0, true><<<(768 / 128) * (8192 / 128), 256, 0, stream>>>(
      Wvb, D, xb, D, Vt, 2 * S, bv, 2 * S, D);

  if (big) {
    float* y = (float*)(P + 2 * nP);
    // 3) scores + mask + exp fused: P = exp(Q K^T) masked, both batches
    gemm256<2><<<dim3(512, 2), 512, 0, stream>>>(
        Qb, D, 0, Kb, D, (size_t)S * D, P, S, nP, am, S, 16, 12, 64);
    // 4) PV both batches: y = P * Vt_b^T (unnormalized), fp32 out
    gemm256<1><<<dim3(96, 2), 512, 0, stream>>>(
        P, S, nP, Vt, 2 * S, (size_t)S, y, D, nY, nullptr, 0, 3, 64, 12);
    // 5) LN + head both batches (LN absorbs softmax normalization)
    ln_head<<<dim3(C, 2), 256, 0, stream>>>(y, gam, bet, wo, bo, out);
  } else {
    float* y = (float*)(P + nP);
    for (int b = 0; b < 2; ++b) {
      gemm256<2><<<dim3(512, 1), 512, 0, stream>>>(
          Qb, D, 0, Kb + (size_t)b * S * D, D, 0, P, S, 0, am + (size_t)b * S, S, 16, 12, 64);
      gemm256<1><<<dim3(96, 1), 512, 0, stream>>>(
          P, S, 0, Vt + (size_t)b * S, 2 * S, 0, y, D, 0, nullptr, 0, 3, 64, 12);
      ln_head<<<dim3(C, 1), 256, 0, stream>>>(y, gam, bet, wo, bo, out + (size_t)b * C);
    }
  }
}

// Round 4
// 304.696 us; speedup vs baseline: 1.5649x; 1.0324x over previous
//
#include <hip/hip_runtime.h>
#include <hip/hip_bf16.h>
#include <hip/hip_fp16.h>

// ---- types ----
typedef _Float16 f16x8 __attribute__((ext_vector_type(8)));
typedef float f32x4 __attribute__((ext_vector_type(4)));
typedef unsigned short us8 __attribute__((ext_vector_type(8)));

#define AS1 __attribute__((address_space(1)))
#define AS3 __attribute__((address_space(3)))

// ---------------- fp32 -> fp16 convert (8 elems/thread) ----------------
__global__ __launch_bounds__(256) void cvt_f32_f16(const float* __restrict__ in,
                                                   unsigned short* __restrict__ out,
                                                   int n8) {
  int i = blockIdx.x * 256 + threadIdx.x;
  if (i >= n8) return;
  const float4* p = (const float4*)in + 2 * (size_t)i;
  float4 a = p[0], b = p[1];
  f16x8 h;
  h[0] = (_Float16)a.x; h[1] = (_Float16)a.y; h[2] = (_Float16)a.z; h[3] = (_Float16)a.w;
  h[4] = (_Float16)b.x; h[5] = (_Float16)b.y; h[6] = (_Float16)b.z; h[7] = (_Float16)b.w;
  *(f16x8*)(out + (size_t)i * 8) = h;
}

// ---------------- 128x128 2-phase NT GEMM (projections only) ----------------
template <int OMODE, bool RBIAS>
__global__ __launch_bounds__(256) void gemm_nt(const unsigned short* __restrict__ A, int lda,
                                               const unsigned short* __restrict__ B, int ldb,
                                               void* __restrict__ Cout, int ldc,
                                               const float* __restrict__ bias,
                                               int N, int K) {
  __shared__ __attribute__((aligned(16))) unsigned short As[128 * 64];
  __shared__ __attribute__((aligned(16))) unsigned short Bs[128 * 64];
  const int nbn = N >> 7;
  const int bm = blockIdx.x / nbn, bn = blockIdx.x % nbn;
  const int tid = threadIdx.x;
  const int w = tid >> 6, l = tid & 63;
  const int wr = w >> 1, wc = w & 1;
  const int lr = l & 15, lg = l >> 4;

  const unsigned short* Ab = A + (size_t)bm * 128 * lda;
  const unsigned short* Bb = B + (size_t)bn * 128 * ldb;

  f32x4 acc[4][4] = {};

  auto ldfrag = [&](const unsigned short* base, int row, int kk) {
    int off = row * 128 + kk * 64 + lg * 16;
    off ^= (row & 7) << 4;
    return *(const f16x8*)((const unsigned char*)base + off);
  };

  for (int kt = 0; kt < K; kt += 64) {
#pragma unroll
    for (int i = 0; i < 4; ++i) {
      const int c = i * 256 + w * 64 + l;
      const int row = c >> 3, col = (((c & 7) ^ (row & 7)) << 3);
      __builtin_amdgcn_global_load_lds((const AS1 void*)(Ab + (size_t)row * lda + kt + col),
                                       (AS3 void*)(As + (i * 256 + w * 64) * 8), 16, 0, 0);
    }
#pragma unroll
    for (int i = 0; i < 4; ++i) {
      const int c = i * 256 + w * 64 + l;
      const int row = c >> 3, col = (((c & 7) ^ (row & 7)) << 3);
      __builtin_amdgcn_global_load_lds((const AS1 void*)(Bb + (size_t)row * ldb + kt + col),
                                       (AS3 void*)(Bs + (i * 256 + w * 64) * 8), 16, 0, 0);
    }
    __syncthreads();
#pragma unroll
    for (int kk = 0; kk < 2; ++kk) {
      f16x8 af[4], bf[4];
#pragma unroll
      for (int mi = 0; mi < 4; ++mi) af[mi] = ldfrag(As, wr * 64 + mi * 16 + lr, kk);
#pragma unroll
      for (int ni = 0; ni < 4; ++ni) bf[ni] = ldfrag(Bs, wc * 64 + ni * 16 + lr, kk);
#pragma unroll
      for (int mi = 0; mi < 4; ++mi)
#pragma unroll
        for (int ni = 0; ni < 4; ++ni)
          acc[mi][ni] = __builtin_amdgcn_mfma_f32_16x16x32_f16(af[mi], bf[ni], acc[mi][ni], 0, 0, 0);
    }
    __syncthreads();
  }

#pragma unroll
  for (int mi = 0; mi < 4; ++mi) {
#pragma unroll
    for (int r = 0; r < 4; ++r) {
      const int row = bm * 128 + wr * 64 + mi * 16 + lg * 4 + r;
      const float badd = RBIAS ? bias[row] : 0.0f;
#pragma unroll
      for (int ni = 0; ni < 4; ++ni) {
        const int col = bn * 128 + wc * 64 + ni * 16 + lr;
        float v = acc[mi][ni][r] + badd;
        if constexpr (OMODE == 0)
          ((unsigned short*)Cout)[(size_t)row * ldc + col] =
              __builtin_bit_cast(unsigned short, (_Float16)v);
        else
          ((float*)Cout)[(size_t)row * ldc + col] = v;
      }
    }
  }
}

// ================= 256x256 8-phase NT GEMM (T1+T2+T3+T4+T5) =================
// Same schedule as the round-3 passing kernel; all LDS/global addresses are
// now thread-constant-base + compile-time immediates (the swizzle XOR term
// ((row>>1)&3)<<4 is mf/nf-independent, and (l>>3)&3 on the staging side).
// Main loop unrolled over tile PAIRS (NT must be even, >= 4).
// vmcnt cadence identical to round 3: VM8 twice/tile steady, drain 8->4->0.
#define MFMA16(a, b, c) __builtin_amdgcn_mfma_f32_16x16x32_f16(a, b, c, 0, 0, 0)
#define VM8 asm volatile("s_waitcnt vmcnt(8)" ::: "memory")
#define VM4 asm volatile("s_waitcnt vmcnt(4)" ::: "memory")
#define VM0 asm volatile("s_waitcnt vmcnt(0)" ::: "memory")
#define VMNONE ((void)0)
#define BARRIER asm volatile("s_barrier" ::: "memory")

#define GLDS(P, EOFF, ROFF)                                                    \
  __builtin_amdgcn_global_load_lds((const AS1 void*)((P) + (EOFF)),            \
                                   (AS3 void*)(lds + (ROFF) + ldsDA), 16, 0, 0)
#define STAGE_A(EOFF, ROFF)                                                    \
  GLDS(sA, EOFF, ROFF);                                                        \
  GLDS(sA2, EOFF, (ROFF) + 1024)
#define STAGE_B(EOFF, ROFF)                                                    \
  GLDS(sB, EOFF, ROFF);                                                        \
  GLDS(sB2, EOFF, (ROFF) + 1024)

#define PH(kk, mh, BOFF, DOB, STMT, VMW)                                       \
  {                                                                            \
    const unsigned char* pa_ = lds + (BOFF) + ((kk) << 14) + aoff;             \
    f16x8 a0 = *(const f16x8*)(pa_ + (4 * (mh) + 0) * 1024);                   \
    f16x8 a1 = *(const f16x8*)(pa_ + (4 * (mh) + 1) * 1024);                   \
    f16x8 a2 = *(const f16x8*)(pa_ + (4 * (mh) + 2) * 1024);                   \
    f16x8 a3 = *(const f16x8*)(pa_ + (4 * (mh) + 3) * 1024);                   \
    if (DOB) {                                                                 \
      const unsigned char* pb_ = lds + (BOFF) + ((kk) << 14) + boff;           \
      vb0 = *(const f16x8*)(pb_ + 0);                                          \
      vb1 = *(const f16x8*)(pb_ + 1024);                                       \
      vb2 = *(const f16x8*)(pb_ + 2048);                                       \
      vb3 = *(const f16x8*)(pb_ + 3072);                                       \
    }                                                                          \
    STMT;                                                                      \
    BARRIER;                                                                   \
    __builtin_amdgcn_s_setprio(1);                                             \
    acc[4 * (mh) + 0][0] = MFMA16(a0, vb0, acc[4 * (mh) + 0][0]);              \
    acc[4 * (mh) + 0][1] = MFMA16(a0, vb1, acc[4 * (mh) + 0][1]);              \
    acc[4 * (mh) + 0][2] = MFMA16(a0, vb2, acc[4 * (mh) + 0][2]);              \
    acc[4 * (mh) + 0][3] = MFMA16(a0, vb3, acc[4 * (mh) + 0][3]);              \
    acc[4 * (mh) + 1][0] = MFMA16(a1, vb0, acc[4 * (mh) + 1][0]);              \
    acc[4 * (mh) + 1][1] = MFMA16(a1, vb1, acc[4 * (mh) + 1][1]);              \
    acc[4 * (mh) + 1][2] = MFMA16(a1, vb2, acc[4 * (mh) + 1][2]);              \
    acc[4 * (mh) + 1][3] = MFMA16(a1, vb3, acc[4 * (mh) + 1][3]);              \
    acc[4 * (mh) + 2][0] = MFMA16(a2, vb0, acc[4 * (mh) + 2][0]);              \
    acc[4 * (mh) + 2][1] = MFMA16(a2, vb1, acc[4 * (mh) + 2][1]);              \
    acc[4 * (mh) + 2][2] = MFMA16(a2, vb2, acc[4 * (mh) + 2][2]);              \
    acc[4 * (mh) + 2][3] = MFMA16(a2, vb3, acc[4 * (mh) + 2][3]);              \
    acc[4 * (mh) + 3][0] = MFMA16(a3, vb0, acc[4 * (mh) + 3][0]);              \
    acc[4 * (mh) + 3][1] = MFMA16(a3, vb1, acc[4 * (mh) + 3][1]);              \
    acc[4 * (mh) + 3][2] = MFMA16(a3, vb2, acc[4 * (mh) + 3][2]);              \
    acc[4 * (mh) + 3][3] = MFMA16(a3, vb3, acc[4 * (mh) + 3][3]);              \
    __builtin_amdgcn_s_setprio(0);                                             \
    VMW;                                                                       \
    BARRIER;                                                                   \
  }

template <int EPI>  // 1 = fp32 store, 2 = fp16 store of (mask ? exp(s) : 0)
__global__ __launch_bounds__(512, 2) void gemm256(
    const unsigned short* __restrict__ A, int lda, size_t sAz,
    const unsigned short* __restrict__ B, int ldb, size_t sBz,
    void* __restrict__ Cout, int ldc, size_t sCz,
    const int* __restrict__ mask, int mS,
    int nbn, int NT, int stripeW, int cpx) {
  __shared__ __attribute__((aligned(16))) unsigned char lds[131072];
  const int tid = threadIdx.x;
  const int wv = tid >> 6, l = tid & 63;
  const int wm = wv >> 2, wn = wv & 3;
  const int lr = l & 15, lg = l >> 4;
  const int z = blockIdx.y;

  const int bid = blockIdx.x;
  int bm, bn;
  if (stripeW) {  // bn-stripe per XCD (keeps B-panels L2-resident); nbn%8==0
    const int xcd = bid & 7, i = bid >> 3;
    bn = xcd * stripeW + (i % stripeW);
    bm = i / stripeW;
  } else {        // bijective chunk swizzle (grid % 8 == 0)
    const int swz = (bid & 7) * cpx + (bid >> 3);
    bm = swz / nbn; bn = swz % nbn;
  }

  const unsigned short* Ab = A + z * sAz + (size_t)bm * 256 * lda;
  const unsigned short* Bb = B + z * sBz + (size_t)bn * 256 * ldb;

  // ---- thread-constant LDS read bases (swizzle XOR folded in) ----
  const int xr = ((lr >> 1) & 3) << 4;
  const int aoff = ((wm * 128 + lr) << 6) + ((lg << 4) ^ xr);
  const int boff = 32768 + ((wn * 64 + lr) << 6) + ((lg << 4) ^ xr);
  const int ldsDA = wv * 2048;

  // ---- per-thread global staging pointers (pre-swizzled source column) ----
  const int colc = ((l & 3) ^ ((l >> 3) & 3)) << 3;  // elements
  const int srow = wv * 32 + (l >> 2);
  const unsigned short* sA  = Ab + (size_t)srow * lda + colc;
  const unsigned short* sA2 = sA + (size_t)16 * lda;
  const unsigned short* sB  = Bb + (size_t)srow * ldb + colc;
  const unsigned short* sB2 = sB + (size_t)16 * ldb;

  f32x4 acc[8][4] = {};
  f16x8 vb0, vb1, vb2, vb3;

  // prologue: tile0 {A-k0, B-k0, A-k1, B-k1} + tile1 {A-k0, B-k0}
  STAGE_A(0, 0);
  STAGE_B(0, 32768);
  STAGE_A(32, 16384);
  STAGE_B(32, 49152);
  STAGE_A(64, 65536);
  STAGE_B(64, 65536 + 32768);
  sA += 64; sA2 += 64; sB += 64; sB2 += 64;  // now at tau = t+1
  VM8;
  BARRIER;

  // main loop over tile pairs (t even). Stages: +32 = k1 of tau(t+1),
  // +64 = k0 of t+2, +96 = k1 of t+2, +128 = k0 of t+3.
  for (int t = 0; t + 3 < NT; t += 2) {
    PH(0, 0, 0, 1, STAGE_A(32, 65536 + 16384), VMNONE);
    PH(0, 1, 0, 0, STAGE_B(32, 65536 + 49152), VM8);
    PH(1, 0, 0, 1, STAGE_A(64, 0), VMNONE);
    PH(1, 1, 0, 0, STAGE_B(64, 32768), VM8);
    PH(0, 0, 65536, 1, STAGE_A(96, 16384), VMNONE);
    PH(0, 1, 65536, 0, STAGE_B(96, 49152), VM8);
    PH(1, 0, 65536, 1, STAGE_A(128, 65536), VMNONE);
    PH(1, 1, 65536, 0, STAGE_B(128, 65536 + 32768), VM8);
    sA += 128; sA2 += 128; sB += 128; sB2 += 128;
  }

  // drain: tile NT-2 (buf0) stages tile NT-1's k1 only, then tile NT-1 (buf1)
  PH(0, 0, 0, 1, STAGE_A(32, 65536 + 16384), VMNONE);
  PH(0, 1, 0, 0, STAGE_B(32, 65536 + 49152), VM8);
  PH(1, 0, 0, 1, , VMNONE);
  PH(1, 1, 0, 0, , VM4);
  PH(0, 0, 65536, 1, , VMNONE);
  PH(0, 1, 65536, 0, , VM0);
  PH(1, 0, 65536, 1, , VMNONE);
  PH(1, 1, 65536, 0, , VMNONE);

  // epilogue: C/D frag col=lr, row=4*lg+reg
  const size_t crow0 = (size_t)bm * 256 + wm * 128;
  const int ccol0 = bn * 256 + wn * 64;
  int mk[4] = {1, 1, 1, 1};
  if constexpr (EPI == 2) {
#pragma unroll
    for (int nf = 0; nf < 4; ++nf)
      mk[nf] = mask[(size_t)z * mS + ccol0 + nf * 16 + lr];
  }
#pragma unroll
  for (int mf = 0; mf < 8; ++mf) {
#pragma unroll
    for (int rr = 0; rr < 4; ++rr) {
      const size_t row = crow0 + mf * 16 + lg * 4 + rr;
      const size_t rb = (size_t)z * sCz + row * (size_t)ldc;
#pragma unroll
      for (int nf = 0; nf < 4; ++nf) {
        const int col = ccol0 + nf * 16 + lr;
        float v = acc[mf][nf][rr];
        if constexpr (EPI == 2) {
          v = mk[nf] ? __expf(v) : 0.0f;
          ((unsigned short*)Cout)[rb + col] =
              __builtin_bit_cast(unsigned short, (_Float16)v);
        } else {
          ((float*)Cout)[rb + col] = v;
        }
      }
    }
  }
}

// ---------------- LayerNorm + output head, one row (768) per block --------
// y arrives UNNORMALIZED (softmax denominator folded out): LN is
// scale-invariant up to eps/(s^2*var) ~ 4e-9 here.
__device__ inline float block_sum(float v, float* sh, int t) {
#pragma unroll
  for (int o = 32; o; o >>= 1) v += __shfl_xor(v, o);
  __syncthreads();
  if ((t & 63) == 0) sh[t >> 6] = v;
  __syncthreads();
  return sh[0] + sh[1] + sh[2] + sh[3];
}

__global__ __launch_bounds__(256) void ln_head(const float* __restrict__ y,
                                               const float* __restrict__ gam,
                                               const float* __restrict__ bet,
                                               const float* __restrict__ wo,
                                               const float* __restrict__ bo,
                                               float* __restrict__ out) {
  const size_t rowi = (size_t)blockIdx.y * 8192 + blockIdx.x;
  const float* yr = y + rowi * 768;
  const int t = threadIdx.x;
  float a0 = yr[t], a1 = yr[t + 256], a2 = yr[t + 512];
  __shared__ float sh[4];
  float s = block_sum(a0 + a1 + a2, sh, t);
  float mu = s * (1.0f / 768.0f);
  float d0 = a0 - mu, d1 = a1 - mu, d2 = a2 - mu;
  float q = block_sum(d0 * d0 + d1 * d1 + d2 * d2, sh, t);
  float rs = rsqrtf(q * (1.0f / 768.0f) + 1e-5f);
  float o = (d0 * rs * gam[t] + bet[t]) * wo[t] +
            (d1 * rs * gam[t + 256] + bet[t + 256]) * wo[t + 256] +
            (d2 * rs * gam[t + 512] + bet[t + 512]) * wo[t + 512];
  o = block_sum(o, sh, t);
  if (t == 0) out[rowi] = o + bo[0];
}

// ---------------- launch ----------------
extern "C" void kernel_launch(void* const* d_in, const int* in_sizes, int n_in,
                              void* d_out, int out_size, void* d_ws, size_t ws_size,
                              hipStream_t stream) {
  const float* x  = (const float*)d_in[0];
  const int*   am = (const int*)d_in[1];
  const float* Wk = (const float*)d_in[2];
  const float* Wv = (const float*)d_in[3];
  const float* bv = (const float*)d_in[4];
  const float* Q  = (const float*)d_in[5];
  const float* gam = (const float*)d_in[6];
  const float* bet = (const float*)d_in[7];
  const float* wo  = (const float*)d_in[8];
  const float* bo  = (const float*)d_in[9];
  float* out = (float*)d_out;

  const int S = 4096, D = 768, C = 8192;
  const size_t nX = (size_t)2 * S * D;
  const size_t nW = (size_t)D * D;
  const size_t nQ = (size_t)C * D;
  const size_t nP = (size_t)C * S;
  const size_t nY = (size_t)C * D;

  unsigned short* xb  = (unsigned short*)d_ws;
  unsigned short* Wkb = xb + nX;
  unsigned short* Wvb = Wkb + nW;
  unsigned short* Qb  = Wvb + nW;
  unsigned short* Kb  = Qb + nQ;
  unsigned short* Vt  = Kb + nX;  // [D][2*S]
  unsigned short* P   = Vt + nX;

  const size_t bigNeed = ((nX * 4 + nW * 2 + 2 * nP) * 2 + 2 * nY * 4);
  const bool big = ws_size >= bigNeed;

  cvt_f32_f16<<<(int)(nX / 8 / 256), 256, 0, stream>>>(x, xb, (int)(nX / 8));
  cvt_f32_f16<<<(int)(nW / 8 / 256), 256, 0, stream>>>(Wk, Wkb, (int)(nW / 8));
  cvt_f32_f16<<<(int)(nW / 8 / 256), 256, 0, stream>>>(Wv, Wvb, (int)(nW / 8));
  cvt_f32_f16<<<(int)(nQ / 8 / 256), 256, 0, stream>>>(Q, Qb, (int)(nQ / 8));

  gemm_nt<0, false><<<(8192 / 128) * (768 / 128), 256, 0, stream>>>(
      xb, D, Wkb, D, Kb, D, nullptr, 768, D);
  gemm_nt<0, true><<<(768 / 128) * (8192 / 128), 256, 0, stream>>>(
      Wvb, D, xb, D, Vt, 2 * S, bv, 2 * S, D);

  if (big) {
    float* y = (float*)(P + 2 * nP);
    // scores + mask + exp fused, both batches; bn-stripe XCD swizzle (W=2)
    gemm256<2><<<dim3(512, 2), 512, 0, stream>>>(
        Qb, D, 0, Kb, D, (size_t)S * D, P, S, nP, am, S, 16, 12, 2, 0);
    // PV both batches (unnormalized), fp32 out; chunk swizzle
    gemm256<1><<<dim3(96, 2), 512, 0, stream>>>(
        P, S, nP, Vt, 2 * S, (size_t)S, y, D, nY, nullptr, 0, 3, 64, 0, 12);
    ln_head<<<dim3(C, 2), 256, 0, stream>>>(y, gam, bet, wo, bo, out);
  } else {
    float* y = (float*)(P + nP);
    for (int b = 0; b < 2; ++b) {
      gemm256<2><<<dim3(512, 1), 512, 0, stream>>>(
          Qb, D, 0, Kb + (size_t)b * S * D, D, 0, P, S, 0, am + (size_t)b * S, S, 16, 12, 2, 0);
      gemm256<1><<<dim3(96, 1), 512, 0, stream>>>(
          P, S, 0, Vt + (size_t)b * S, 2 * S, 0, y, D, 0, nullptr, 0, 3, 64, 0, 12);
      ln_head<<<dim3(C, 1), 256, 0, stream>>>(y, gam, bet, wo, bo, out + (size_t)b * C);
    }
  }
}